// Round 1
// baseline (1660.457 us; speedup 1.0000x reference)
//
#include <hip/hip_runtime.h>

#define D0 128
#define D1 64
#define D2 32
#define DL 3

__device__ __forceinline__ float sigf(float x) {
    // sigmoid(x) = 1/(1+2^(-x*log2(e))); v_exp_f32 + v_rcp_f32, ~1 ulp
    float e = __builtin_amdgcn_exp2f(-1.44269504088896340736f * x);
    return __builtin_amdgcn_rcpf(1.0f + e);
}

__global__ __launch_bounds__(256, 2) void sindy_fused(
    const float* __restrict__ x,  const float* __restrict__ dx,
    const float* __restrict__ W1, const float* __restrict__ b1,
    const float* __restrict__ W2, const float* __restrict__ b2,
    const float* __restrict__ W3, const float* __restrict__ b3,
    const float* __restrict__ V1, const float* __restrict__ c1,
    const float* __restrict__ V2, const float* __restrict__ c2,
    const float* __restrict__ V3, const float* __restrict__ c3,
    const float* __restrict__ Ew, const float* __restrict__ Eb,
    float* __restrict__ out, int n)
{
    const int tid = threadIdx.x;
    const int s0  = blockIdx.x * 256;

    // Transposed staging tiles [k][sample], pad 257 -> bank = (k+s)%32, conflict-free.
    __shared__ float bufA[16][257];
    __shared__ float bufB[16][257];

    // ---------------- encoder layer 1: 128 -> 64 (k-chunked via LDS) ----------------
    float h1[D1], dh1[D1];
    #pragma unroll
    for (int j = 0; j < D1; ++j) { h1[j] = b1[j]; dh1[j] = 0.0f; }

    for (int c = 0; c < 8; ++c) {
        __syncthreads();
        #pragma unroll
        for (int i = 0; i < 4; ++i) {
            int idx4 = tid + i * 256;          // 1024 float4 = 256 samples x 16 k
            int s  = idx4 >> 2;
            int kb = (idx4 & 3) * 4;
            const float4 gx  = *(const float4*)(x  + (size_t)(s0 + s) * D0 + c * 16 + kb);
            const float4 gdx = *(const float4*)(dx + (size_t)(s0 + s) * D0 + c * 16 + kb);
            bufA[kb + 0][s] = gx.x;  bufA[kb + 1][s] = gx.y;
            bufA[kb + 2][s] = gx.z;  bufA[kb + 3][s] = gx.w;
            bufB[kb + 0][s] = gdx.x; bufB[kb + 1][s] = gdx.y;
            bufB[kb + 2][s] = gdx.z; bufB[kb + 3][s] = gdx.w;
        }
        __syncthreads();
        #pragma unroll
        for (int kk = 0; kk < 16; kk += 8) {
            float xv[8], dxv[8];
            #pragma unroll
            for (int u = 0; u < 8; ++u) { xv[u] = bufA[kk + u][tid]; dxv[u] = bufB[kk + u][tid]; }
            #pragma unroll
            for (int j = 0; j < D1; ++j) {
                #pragma unroll
                for (int u = 0; u < 8; ++u) {
                    float w = W1[j * D0 + c * 16 + kk + u];   // uniform -> s_load
                    h1[j]  = fmaf(w, xv[u],  h1[j]);
                    dh1[j] = fmaf(w, dxv[u], dh1[j]);
                }
            }
        }
    }
    #pragma unroll
    for (int j = 0; j < D1; ++j) {
        float sv = sigf(h1[j]);
        h1[j]  = sv;
        dh1[j] = sv * (1.0f - sv) * dh1[j];
    }

    // ---------------- encoder layer 2: 64 -> 32 ----------------
    float h2[D2], dh2[D2];
    #pragma unroll
    for (int j = 0; j < D2; ++j) {
        float a = b2[j], da = 0.0f;
        #pragma unroll
        for (int k = 0; k < D1; ++k) {
            float w = W2[j * D1 + k];
            a  = fmaf(w, h1[k],  a);
            da = fmaf(w, dh1[k], da);
        }
        float sv = sigf(a);
        h2[j]  = sv;
        dh2[j] = sv * (1.0f - sv) * da;
    }

    // ---------------- encoder layer 3: 32 -> 3 (linear) ----------------
    float z[DL], dz[DL];
    #pragma unroll
    for (int j = 0; j < DL; ++j) {
        float a = b3[j], da = 0.0f;
        #pragma unroll
        for (int k = 0; k < D2; ++k) {
            float w = W3[j * D2 + k];
            a  = fmaf(w, h2[k],  a);
            da = fmaf(w, dh2[k], da);
        }
        z[j] = a; dz[j] = da;
    }

    // ---------------- SINDy library (22 terms) + dzb ----------------
    float th[22];
    th[0] = 1.0f; th[1] = 1.0f; th[2] = 1.0f;
    th[3] = z[0]; th[4] = z[1]; th[5] = z[2];
    {
        int t = 6;
        #pragma unroll
        for (int i = 0; i < 3; ++i)
            #pragma unroll
            for (int j = i; j < 3; ++j) th[t++] = z[i] * z[j];
        #pragma unroll
        for (int i = 0; i < 3; ++i)
            #pragma unroll
            for (int j = i; j < 3; ++j)
                #pragma unroll
                for (int k = j; k < 3; ++k) th[t++] = z[i] * z[j] * z[k];
    }
    float dzb[DL];
    #pragma unroll
    for (int j = 0; j < DL; ++j) {
        float a = Eb[j];
        #pragma unroll
        for (int q = 0; q < 22; ++q) a = fmaf(Ew[j * 22 + q], th[q], a);
        dzb[j] = a;
    }

    // ---------------- write z, dz, dzb ----------------
    {
        const size_t s  = (size_t)(s0 + tid);
        const size_t n3 = (size_t)n * 3;
        #pragma unroll
        for (int j = 0; j < DL; ++j) {
            out[           s * 3 + j] = z[j];
            out[n3       + s * 3 + j] = dz[j];
            out[2 * n3   + s * 3 + j] = dzb[j];
        }
    }

    // ---------------- decoder layer 1: 3 -> 32 ----------------
    float g1[D2], dg1[D2];
    #pragma unroll
    for (int j = 0; j < D2; ++j) {
        float a = c1[j], da = 0.0f;
        #pragma unroll
        for (int k = 0; k < DL; ++k) {
            float w = V1[j * DL + k];
            a  = fmaf(w, z[k],   a);
            da = fmaf(w, dzb[k], da);
        }
        float sv = sigf(a);
        g1[j]  = sv;
        dg1[j] = sv * (1.0f - sv) * da;
    }

    // ---------------- decoder layer 2: 32 -> 64 ----------------
    float g2[D1], dg2[D1];
    #pragma unroll
    for (int j = 0; j < D1; ++j) {
        float a = c2[j], da = 0.0f;
        #pragma unroll
        for (int k = 0; k < D2; ++k) {
            float w = V2[j * D2 + k];
            a  = fmaf(w, g1[k],  a);
            da = fmaf(w, dg1[k], da);
        }
        float sv = sigf(a);
        g2[j]  = sv;
        dg2[j] = sv * (1.0f - sv) * da;
    }

    // ---------------- decoder layer 3: 64 -> 128 (staged stores) ----------------
    float* oxb  = out + (size_t)n * 9;
    float* odxb = out + (size_t)n * 137;
    for (int jc = 0; jc < 8; ++jc) {
        float xo[16], dxo[16];
        #pragma unroll
        for (int jj = 0; jj < 16; ++jj) {
            int j = jc * 16 + jj;
            float a = c3[j], da = 0.0f;
            #pragma unroll
            for (int k = 0; k < D1; ++k) {
                float w = V3[j * D1 + k];
                a  = fmaf(w, g2[k],  a);
                da = fmaf(w, dg2[k], da);
            }
            xo[jj] = a; dxo[jj] = da;
        }
        __syncthreads();
        #pragma unroll
        for (int jj = 0; jj < 16; ++jj) {
            bufA[jj][tid] = xo[jj];
            bufB[jj][tid] = dxo[jj];
        }
        __syncthreads();
        #pragma unroll
        for (int i = 0; i < 4; ++i) {
            int idx4 = tid + i * 256;
            int s  = idx4 >> 2;
            int jb = (idx4 & 3) * 4;
            float4 v, dv;
            v.x  = bufA[jb + 0][s]; v.y  = bufA[jb + 1][s];
            v.z  = bufA[jb + 2][s]; v.w  = bufA[jb + 3][s];
            dv.x = bufB[jb + 0][s]; dv.y = bufB[jb + 1][s];
            dv.z = bufB[jb + 2][s]; dv.w = bufB[jb + 3][s];
            *(float4*)(oxb  + (size_t)(s0 + s) * D0 + jc * 16 + jb) = v;
            *(float4*)(odxb + (size_t)(s0 + s) * D0 + jc * 16 + jb) = dv;
        }
    }
}

extern "C" void kernel_launch(void* const* d_in, const int* in_sizes, int n_in,
                              void* d_out, int out_size, void* d_ws, size_t ws_size,
                              hipStream_t stream) {
    const float* x  = (const float*)d_in[0];
    const float* dx = (const float*)d_in[1];
    const float* W1 = (const float*)d_in[2];
    const float* b1 = (const float*)d_in[3];
    const float* W2 = (const float*)d_in[4];
    const float* b2 = (const float*)d_in[5];
    const float* W3 = (const float*)d_in[6];
    const float* b3 = (const float*)d_in[7];
    const float* V1 = (const float*)d_in[8];
    const float* c1 = (const float*)d_in[9];
    const float* V2 = (const float*)d_in[10];
    const float* c2 = (const float*)d_in[11];
    const float* V3 = (const float*)d_in[12];
    const float* c3 = (const float*)d_in[13];
    const float* Ew = (const float*)d_in[14];
    const float* Eb = (const float*)d_in[15];

    const int n = in_sizes[0] / D0;      // 262144
    const int grid = n / 256;            // 1024 blocks, one sample per thread

    sindy_fused<<<grid, 256, 0, stream>>>(x, dx, W1, b1, W2, b2, W3, b3,
                                          V1, c1, V2, c2, V3, c3, Ew, Eb,
                                          (float*)d_out, n);
}